// Round 10
// baseline (157.414 us; speedup 1.0000x reference)
//
#include <hip/hip_runtime.h>

// TorchPatchNN: unfold(7x7) -> NN argmin over 8100 keys (D=147) -> gather value -> fold mean.
// Round 15: switch k_nn to mfma_f32_32x32x16_f16. R14 accounting: MFMA-pipe duty ~47%
//  (240 x 19.4cyc @ 844 FLOP/cyc/SIMD for 16x16). The 32x32 shape runs 969 FLOP/cyc/SIMD
//  (2382 vs 2075 TF ubench): 120 instr x 33.8cyc = 4056 vs 4656 cyc/wave (-13% pipe) and
//  halves MFMA issue slots. Held constant: 128x128 tile, 64 AGPR acc (4x f32x16), 16 1KB
//  frag loads/chunk/wave, barrier-free loop, launch_bounds(256,3), XCD swizzle, setprio.
//  - k_prep now writes 32x32 operand order: lane=m|n (lane&31), k = c*32 + s*16 +
//    (lane>>5)*8 + j  (symmetric analog of the verified 16x16 layout).
//  - Epilogue C-mapping (m74/m101-verified): col=lane&31, row=(reg&3)+8*(reg>>2)+4*(lane>>5);
//    shfl_xor(1) col-pair pre-combine keeps redu at [128][33] u64 (33.8KB).
//  Bucket ledger: non-k_nn ~74-78us stable; k_prep+k_fold ~15us; rest = fixed overhead ->
//  k_nn is the only attackable term left.
//  Falsifiers: absmax explodes => 32x32 A/B layout assumption wrong, revert. dur flat =>
//  MFMA pipe not binding => cooperative single-launch fusion next.

#define NQ 8100
#define NK 8100
#define DD 147
#define HO 90
#define IMG 96
#define NCH 5                 // K chunks of 32 (2 x K=16 subtiles per chunk)
#define CST 262144            // f16 per chunk plane
#define ARRN (NCH * CST)      // f16 per array

typedef _Float16 half8 __attribute__((ext_vector_type(8)));
typedef float f32x16 __attribute__((ext_vector_type(16)));

// ---------------- prep: split Q/K into fp16 hi/lo (32x32 frag order) + key norms ----------
__global__ void k_prep(const float* __restrict__ query, const float* __restrict__ key,
                       _Float16* __restrict__ Qh, _Float16* __restrict__ Ql,
                       _Float16* __restrict__ Kh, _Float16* __restrict__ Kl,
                       float* __restrict__ kn, unsigned long long* __restrict__ fidx64) {
    const int bx = blockIdx.x;
    const bool isK = (blockIdx.y != 0);

    if (bx >= 640) {                      // fused k_kn region: 128 blocks on y==1
        if (!isK) return;
        int wave = threadIdx.x >> 6, lane = threadIdx.x & 63;
        int kb = ((bx - 640) * 4 + wave) * 16;
        for (int r = 0; r < 16; ++r) {
            int k = kb + r;
            float s = 0.f;
            if (k < NK)
                for (int d = lane; d < DD; d += 64) {
                    float v = key[k * DD + d];
                    s += v * v;
                }
#pragma unroll
            for (int off = 32; off; off >>= 1) s += __shfl_down(s, off, 64);
            if (lane == 0) {
                kn[k] = (k < NK) ? s : 1e30f;
                fidx64[k] = 0xFFFFFFFFFFFFFFFFull;   // ws re-poisoned every launch
            }
        }
        return;
    }

    // 32x32 frag-linear decomposition: g8 = ((c*256 + t32)*2 + s)*64 + lane
    int g8 = bx * 256 + threadIdx.x;            // 0 .. 163839 (ARRN/8)
    int lane = g8 & 63;
    int s16 = (g8 >> 6) & 1;                    // K=16 subtile within chunk
    int t32 = (g8 >> 7) & 255;                  // 32-row tile
    int c = g8 >> 15;                           // chunk
    int col = t32 * 32 + (lane & 31);           // m (or n) index
    int kbase = c * 32 + s16 * 16 + (lane >> 5) * 8;

    float v[8];
#pragma unroll
    for (int j = 0; j < 8; ++j) {
        int k = kbase + j;
        float x = 0.f;
        if (k < DD && col < NQ) {
            if (isK) {
                x = key[col * DD + k];
            } else {
                int c3 = k / 49, r2 = k - 49 * c3;
                int rr = r2 / 7, ss = r2 - 7 * rr;
                int y = col / HO, xx = col - HO * y;
                x = query[(c3 * IMG + y + rr) * IMG + xx + ss];
            }
        }
        v[j] = x;
    }
    half8 h8, l8;
#pragma unroll
    for (int j = 0; j < 8; ++j) {
        _Float16 h = (_Float16)v[j];
        h8[j] = h;
        l8[j] = (_Float16)(v[j] - (float)h);   // UNSCALED lo (merged-acc scheme)
    }
    if (isK) {
        *(half8*)(Kh + g8 * 8) = h8;
        *(half8*)(Kl + g8 * 8) = l8;
    } else {
        *(half8*)(Qh + g8 * 8) = h8;
        *(half8*)(Ql + g8 * 8) = l8;
    }
}

// ---------------- main: merged-acc split-f16 32x32x16 MFMA Q.K^T + fused argmin ----------
// Barrier-free K-loop, single acc[2][2] of f32x16 (64 AGPR), 3 blocks/CU target.
__launch_bounds__(256, 3)
__global__ void k_nn(const _Float16* __restrict__ Qh, const _Float16* __restrict__ Ql,
                     const _Float16* __restrict__ Kh, const _Float16* __restrict__ Kl,
                     const float* __restrict__ kn, unsigned long long* __restrict__ out) {
    __shared__ __align__(16) char smem[33792];   // epilogue reduction only: [128][33] u64

    const int tid = (int)threadIdx.x;
    const int wave = tid >> 6, lane = tid & 63;
    const int hi = lane >> 5;

    // XCD-aware swizzle: blockIdx%8 == XCD. Per XCD: 16qt x 32kt rectangle =>
    // Q 1.28 MB + K 2.56 MB = 3.84 MB <= 4 MiB L2.
    const int b = (int)blockIdx.x;
    const int xcd = b & 7;
    const int i = b >> 3;                         // 0..511 within XCD
    const int qt = (xcd >> 1) * 16 + (i & 15);
    const int kt = (xcd & 1) * 32 + (i >> 4);

    const int mbase = (wave >> 1) * 64;           // wave tile: 64x64 within 128x128
    const int nbase = (wave & 1) * 64;
    const int q0 = qt * 128, n0 = kt * 128;

    // frag-linear global bases: tile32 index = qt*4 + (wave>>1)*2 + mt (A) etc.
    const _Float16* gQh = Qh + ((qt * 4 + (wave >> 1) * 2) * 2) * 512 + lane * 8;
    const _Float16* gQl = Ql + ((qt * 4 + (wave >> 1) * 2) * 2) * 512 + lane * 8;
    const _Float16* gKh = Kh + ((kt * 4 + (wave & 1) * 2) * 2) * 512 + lane * 8;
    const _Float16* gKl = Kl + ((kt * 4 + (wave & 1) * 2) * 2) * 512 + lane * 8;

    f32x16 acc[2][2];                             // 64 AGPR
#pragma unroll
    for (int ii = 0; ii < 2; ++ii)
#pragma unroll
        for (int j = 0; j < 2; ++j)
            acc[ii][j] = (f32x16)0.f;

#pragma unroll
    for (int c = 0; c < NCH; ++c) {
        // 16 independent coalesced 16B loads; no barrier anywhere in the K-loop.
        half8 ah[2][2], al[2][2], bh[2][2], bl[2][2];   // [mt|nt][s]
#pragma unroll
        for (int mt = 0; mt < 2; ++mt)
#pragma unroll
            for (int s = 0; s < 2; ++s) {
                ah[mt][s] = *(const half8*)(gQh + c * CST + (mt * 2 + s) * 512);
                al[mt][s] = *(const half8*)(gQl + c * CST + (mt * 2 + s) * 512);
            }
#pragma unroll
        for (int nt = 0; nt < 2; ++nt)
#pragma unroll
            for (int s = 0; s < 2; ++s) {
                bh[nt][s] = *(const half8*)(gKh + c * CST + (nt * 2 + s) * 512);
                bl[nt][s] = *(const half8*)(gKl + c * CST + (nt * 2 + s) * 512);
            }

        __builtin_amdgcn_s_setprio(1);
#pragma unroll
        for (int s = 0; s < 2; ++s)
#pragma unroll
            for (int nt = 0; nt < 2; ++nt)
#pragma unroll
                for (int mt = 0; mt < 2; ++mt) {
                    acc[mt][nt] = __builtin_amdgcn_mfma_f32_32x32x16_f16(ah[mt][s], bh[nt][s], acc[mt][nt], 0, 0, 0);
                    acc[mt][nt] = __builtin_amdgcn_mfma_f32_32x32x16_f16(ah[mt][s], bl[nt][s], acc[mt][nt], 0, 0, 0);
                    acc[mt][nt] = __builtin_amdgcn_mfma_f32_32x32x16_f16(al[mt][s], bh[nt][s], acc[mt][nt], 0, 0, 0);
                }
        __builtin_amdgcn_s_setprio(0);
    }

    // epilogue: dist = kn - 2*acc; C layout: col=lane&31, row=(reg&3)+8*(reg>>2)+4*hi.
    // Per-lane min over nt (cols n, n+32), then shfl_xor(1) col-pair combine -> [128][33].
    float knv[2];
    int nglob[2];
#pragma unroll
    for (int nt = 0; nt < 2; ++nt) {
        nglob[nt] = n0 + nbase + nt * 32 + (lane & 31);
        knv[nt] = kn[nglob[nt]];
    }
    unsigned long long* redu = (unsigned long long*)smem;   // [128][33] u64 (33.8 KiB)
    const int cidx = (nbase >> 2) + ((lane & 31) >> 1);     // 0..31 after pair-combine

#pragma unroll
    for (int mt = 0; mt < 2; ++mt)
#pragma unroll
        for (int reg = 0; reg < 16; ++reg) {
            float bv = 1e38f;
            int bn = 0x7fffffff;
#pragma unroll
            for (int nt = 0; nt < 2; ++nt) {   // ascending n within lane -> strict < ok
                float d = knv[nt] - 2.0f * acc[mt][nt][reg];
                if (d < bv) { bv = d; bn = nglob[nt]; }
            }
            unsigned u = __float_as_uint(bv);
            u = (u & 0x80000000u) ? ~u : (u | 0x80000000u);   // order-preserving map
            unsigned long long pk = ((unsigned long long)u << 32) | (unsigned)bn;
            unsigned long long po = __shfl_xor(pk, 1, 64);    // partner col (n^1), same row
            pk = (po < pk) ? po : pk;
            if (!(lane & 1)) {
                int m = mbase + mt * 32 + (reg & 3) + 8 * (reg >> 2) + 4 * hi;
                redu[m * 33 + cidx] = pk;
            }
        }
    __syncthreads();

    {   // all 256 threads: 2 per row, 16 u64-min each, pair-combine via shfl
        int row = tid >> 1;
        int base = (tid & 1) * 16;
        unsigned long long best = 0xFFFFFFFFFFFFFFFFull;
        const unsigned long long* rp = redu + row * 33 + base;
#pragma unroll
        for (int t2 = 0; t2 < 16; ++t2) {
            unsigned long long v = rp[t2];
            best = (v < best) ? v : best;
        }
        unsigned long long other = __shfl_xor(best, 1, 64);
        best = (other < best) ? other : best;
        if (!(tid & 1)) atomicMin(&out[q0 + row], best);
    }
}

// ---------------- gather + fold (overlap-add mean) ----------------
// 8 lanes per output pixel: lane-slot s=0..6 handles patch-row i=s (7 j-loads, ILP 7),
// s=7 idle; shfl_down(width=8) tree reduces; s==0 divides by ANALYTIC count and stores.
__global__ void k_fold(const float* __restrict__ value,
                       const unsigned long long* __restrict__ fidx64,
                       float* __restrict__ out) {
    int t = blockIdx.x * 256 + threadIdx.x;   // 3*96*96*8 = 221184
    int pix = t >> 3, s = t & 7;
    if (pix >= 3 * IMG * IMG) return;
    int c = pix / (IMG * IMG);
    int rem = pix % (IMG * IMG);
    int Y = rem / IMG, X = rem % IMG;

    float partial = 0.f;
    int yy = Y - s;
    if (s < 7 && (unsigned)yy < (unsigned)HO) {
        const unsigned* fidx32 = (const unsigned*)fidx64;   // low word = row index
        const float* vbase = value + c * 49 + s * 7;
        int rows[7];
        bool oks[7];
#pragma unroll
        for (int j = 0; j < 7; ++j) {
            int xx = X - j;
            bool ok = (unsigned)xx < (unsigned)HO;
            int p = ok ? (yy * HO + xx) : 0;
            rows[j] = (int)fidx32[2 * p];
            oks[j] = ok;
        }
#pragma unroll
        for (int j = 0; j < 7; ++j) {
            float v = vbase[rows[j] * DD + j];   // always in-bounds (row 0 when masked)
            if (oks[j]) partial += v;
        }
    }
    partial += __shfl_down(partial, 4, 8);
    partial += __shfl_down(partial, 2, 8);
    partial += __shfl_down(partial, 1, 8);
    if (s == 0) {
        int i0 = max(0, Y - (HO - 1)), i1 = min(6, Y);
        int j0 = max(0, X - (HO - 1)), j1 = min(6, X);
        float cnt = (float)((i1 - i0 + 1) * (j1 - j0 + 1));
        out[pix] = partial / cnt;
    }
}

extern "C" void kernel_launch(void* const* d_in, const int* in_sizes, int n_in,
                              void* d_out, int out_size, void* d_ws, size_t ws_size,
                              hipStream_t stream) {
    const float* query = (const float*)d_in[0];
    const float* key   = (const float*)d_in[1];
    const float* value = (const float*)d_in[2];
    float* out = (float*)d_out;

    _Float16* Qh = (_Float16*)d_ws;           // ARRN f16 each
    _Float16* Ql = Qh + ARRN;
    _Float16* Kh = Ql + ARRN;
    _Float16* Kl = Kh + ARRN;
    float* kn = (float*)(Kl + ARRN);          // 8192 f32
    unsigned long long* fidx64 = (unsigned long long*)(kn + 8192);   // 8192 u64

    dim3 gp(768, 2);   // 640 split blocks + 128 fused-kn blocks (y==1)
    k_prep<<<gp, 256, 0, stream>>>(query, key, Qh, Ql, Kh, Kl, kn, fidx64);
    k_nn<<<4096, 256, 0, stream>>>(Qh, Ql, Kh, Kl, kn, fidx64);
    k_fold<<<864, 256, 0, stream>>>(value, fidx64, out);
}